// Round 4
// baseline (1618.211 us; speedup 1.0000x reference)
//
#include <hip/hip_runtime.h>
#include <hip/hip_bf16.h>

// AdaptiveEdgeGAT: N=50000, E=800000, IN=OUT=128, EDGE=64, H=4, D=32
// CSR (sort-by-dst) + gather-based segmented reductions: zero data-path atomics.
// R4: 4-wave per-node kernel (parallel msg gather, W^T in regs for edge GEMM),
//     wave-per-edge logits kernel.

#define N_NODES 50000
#define N_EDGES 800000
#define IN_DIM 128
#define OUT_DIM 128
#define EDGE_DIM 64
#define HEADS 4
#define HEAD_DIM 32
#define NEG_SLOPE 0.2f

typedef __hip_bfloat16 bf16;
typedef unsigned short u16;
typedef unsigned int u32;

// canonical f32 weight-block offsets (floats)
#define OFF_WSRC 0
#define OFF_BSRC 16384
#define OFF_WDST 16512
#define OFF_BDST 32896
#define OFF_ATTN 33024
#define OFF_WEDGE 33152
#define OFF_BEDGE 41344
#define OFF_WGATE 41472
#define OFF_BGATE 74240
#define OFF_WOUT 74368
#define OFF_BOUT 90752
#define OFF_WEDGE_T 90880   // transposed W_edge: [col][k] = [128][64]
#define W_TOTAL 99072

__device__ __forceinline__ float b2f_raw(u16 v) {
    return __uint_as_float(((u32)v) << 16);
}
__device__ __forceinline__ float b2f(bf16 v) { return __bfloat162float(v); }
__device__ __forceinline__ u16 f2b_u16(float f) {
    bf16 b = __float2bfloat16(f);
    union { bf16 b; u16 u; } cv; cv.b = b; return cv.u;
}
__device__ __forceinline__ float loadin(const void* p, long i, int isbf) {
    return isbf ? b2f_raw(((const u16*)p)[i]) : ((const float*)p)[i];
}

// ---------- dtype detector ----------
__global__ __launch_bounds__(256) void k_detect(const void* node, int* flag) {
    __shared__ int cnt[256];
    int c = 0;
    for (int i = threadIdx.x; i < 8192; i += 256) {
        float v = b2f_raw(((const u16*)node)[i]);
        float a = fabsf(v);
        if ((a >= 1e-4f && a <= 50.f) || v == 0.f) c++;
    }
    cnt[threadIdx.x] = c;
    __syncthreads();
    for (int s = 128; s > 0; s >>= 1) {
        if (threadIdx.x < s) cnt[threadIdx.x] += cnt[threadIdx.x + s];
        __syncthreads();
    }
    if (threadIdx.x == 0) flag[0] = (cnt[0] >= (8192 * 85) / 100) ? 1 : 0;
}

// ---------- canonicalize weights to f32 (+ transposed W_edge) ----------
__global__ __launch_bounds__(256) void k_wconv(const void* Wsrc, const void* bsrc,
                                               const void* Wdst, const void* bdst,
                                               const void* attn, const void* Wedge, const void* bedge,
                                               const void* Wgate, const void* bgate,
                                               const void* Wout, const void* bout,
                                               float* w, const int* flag) {
    int i = blockIdx.x * 256 + threadIdx.x;
    if (i >= W_TOTAL) return;
    int f = flag[0];
    const void* p; long off;
    if (i < OFF_BSRC)         { p = Wsrc;  off = i - OFF_WSRC; }
    else if (i < OFF_WDST)    { p = bsrc;  off = i - OFF_BSRC; }
    else if (i < OFF_BDST)    { p = Wdst;  off = i - OFF_WDST; }
    else if (i < OFF_ATTN)    { p = bdst;  off = i - OFF_BDST; }
    else if (i < OFF_WEDGE)   { p = attn;  off = i - OFF_ATTN; }
    else if (i < OFF_BEDGE)   { p = Wedge; off = i - OFF_WEDGE; }
    else if (i < OFF_WGATE)   { p = bedge; off = i - OFF_BEDGE; }
    else if (i < OFF_BGATE)   { p = Wgate; off = i - OFF_WGATE; }
    else if (i < OFF_WOUT)    { p = bgate; off = i - OFF_BGATE; }
    else if (i < OFF_BOUT)    { p = Wout;  off = i - OFF_WOUT; }
    else if (i < OFF_WEDGE_T) { p = bout;  off = i - OFF_BOUT; }
    else { // transposed W_edge: wt[col*64+k] = W_edge[k*128+col]
        int idx = i - OFF_WEDGE_T;
        int col = idx >> 6, k = idx & 63;
        w[i] = loadin(Wedge, (long)k * OUT_DIM + col, f);
        return;
    }
    w[i] = loadin(p, off, f);
}

// ---------- zero degree counters ----------
__global__ __launch_bounds__(256) void k_zero(int* __restrict__ deg) {
    int i = blockIdx.x * 256 + threadIdx.x;
    if (i < N_NODES) deg[i] = 0;
}

// ---------- degree histogram ----------
__global__ __launch_bounds__(256) void k_hist(const int* __restrict__ dst, int* __restrict__ deg) {
    int e = blockIdx.x * 256 + threadIdx.x;
    if (e < N_EDGES) atomicAdd(&deg[dst[e]], 1);
}

// ---------- exclusive prefix sum (single block) -> rowptr, cursor ----------
__global__ __launch_bounds__(1024) void k_scan(const int* __restrict__ deg,
                                               int* __restrict__ rowptr,
                                               int* __restrict__ cursor) {
    __shared__ int buf[1024];
    __shared__ int carry;
    int tid = threadIdx.x;
    if (tid == 0) carry = 0;
    __syncthreads();
    for (int base = 0; base <= N_NODES; base += 1024) {
        int i = base + tid;
        int v = (i < N_NODES) ? deg[i] : 0;
        buf[tid] = v;
        __syncthreads();
        for (int s = 1; s < 1024; s <<= 1) {
            int add = (tid >= s) ? buf[tid - s] : 0;
            __syncthreads();
            buf[tid] += add;
            __syncthreads();
        }
        int excl = carry + buf[tid] - v;
        if (i <= N_NODES) {
            rowptr[i] = excl;
            if (i < N_NODES) cursor[i] = excl;
        }
        __syncthreads();
        if (tid == 1023) carry += buf[1023];
        __syncthreads();
    }
}

// ---------- scatter edge ids into dst-sorted order ----------
__global__ __launch_bounds__(256) void k_permute(const int* __restrict__ dst,
                                                 int* __restrict__ cursor, int* __restrict__ perm) {
    int e = blockIdx.x * 256 + threadIdx.x;
    if (e >= N_EDGES) return;
    int p = atomicAdd(&cursor[dst[e]], 1);
    perm[p] = e;
}

// ---------- node projections ----------
#define PROJ_ROWS 16
__global__ __launch_bounds__(128) void k_proj(const void* __restrict__ node,
                                              const float* __restrict__ w, const int* __restrict__ flag,
                                              bf16* __restrict__ f_src, bf16* __restrict__ f_dst) {
    __shared__ float lds[PROJ_ROWS][IN_DIM];
    int isbf = flag[0];
    int col = threadIdx.x;
    long row0 = (long)blockIdx.x * PROJ_ROWS;
    for (int i = col; i < PROJ_ROWS * IN_DIM; i += 128)
        lds[i >> 7][i & 127] = loadin(node, row0 * IN_DIM + i, isbf);
    __syncthreads();
    float accs[PROJ_ROWS], accd[PROJ_ROWS];
    float bsv = w[OFF_BSRC + col], bdv = w[OFF_BDST + col];
#pragma unroll
    for (int r = 0; r < PROJ_ROWS; r++) { accs[r] = bsv; accd[r] = bdv; }
    for (int k = 0; k < IN_DIM; k++) {
        float ws = w[OFF_WSRC + k * OUT_DIM + col];
        float wd = w[OFF_WDST + k * OUT_DIM + col];
#pragma unroll
        for (int r = 0; r < PROJ_ROWS; r++) {
            float x = lds[r][k];
            accs[r] += x * ws;
            accd[r] += x * wd;
        }
    }
#pragma unroll
    for (int r = 0; r < PROJ_ROWS; r++) {
        f_src[(row0 + r) * OUT_DIM + col] = __float2bfloat16(accs[r]);
        f_dst[(row0 + r) * OUT_DIM + col] = __float2bfloat16(accd[r]);
    }
}

// ---------- GATv2 logits: one wave per edge, 8 edges per wave ----------
__global__ __launch_bounds__(256) void k_logits2(const bf16* __restrict__ f_src,
                                                 const bf16* __restrict__ f_dst,
                                                 const int* __restrict__ src, const int* __restrict__ dst,
                                                 const float* __restrict__ w,
                                                 bf16* __restrict__ logits) {
    const int wv = threadIdx.x >> 6, lane = threadIdx.x & 63;
    // lane covers cols {2*lane, 2*lane+1}; head = lane>>4
    const float2 awp = ((const float2*)(w + OFF_ATTN))[lane];
    const u32* fs = (const u32*)f_src;
    const u32* fd = (const u32*)f_dst;
    long e0 = ((long)blockIdx.x * 4 + wv) * 8;
#pragma unroll
    for (int it = 0; it < 8; it++) {
        long e = e0 + it;
        int s = src[e], d = dst[e];
        u32 pa = fs[(long)s * 64 + lane];
        u32 pb = fd[(long)d * 64 + lane];
        float v0 = b2f_raw((u16)(pa & 0xFFFF)) + b2f_raw((u16)(pb & 0xFFFF));
        float v1 = b2f_raw((u16)(pa >> 16)) + b2f_raw((u16)(pb >> 16));
        v0 = v0 > 0.f ? v0 : NEG_SLOPE * v0;
        v1 = v1 > 0.f ? v1 : NEG_SLOPE * v1;
        float p = v0 * awp.x + v1 * awp.y;
#pragma unroll
        for (int m = 1; m <= 8; m <<= 1) p += __shfl_xor(p, m, 16);
        int pv = (int)f2b_u16(p);       // lanes 0,16,32,48 hold the 4 head sums
        int p1 = __shfl(pv, 16, 64);
        int p2 = __shfl(pv, 32, 64);
        int p3 = __shfl(pv, 48, 64);
        if (lane == 0)
            ((uint2*)logits)[e] = make_uint2((u32)(u16)pv | ((u32)(u16)p1 << 16),
                                             (u32)(u16)p2 | ((u32)(u16)p3 << 16));
    }
}

// ---------- per-node: softmax stats + msg gather + edge GEMM + max ----------
#define CAP 192
__global__ __launch_bounds__(256) void k_node2(const int* __restrict__ rowptr,
                                               const int* __restrict__ perm,
                                               const int* __restrict__ src,
                                               const bf16* __restrict__ f_src,
                                               const bf16* __restrict__ logits,
                                               const void* __restrict__ edge_feat,
                                               const float* __restrict__ w, const int* __restrict__ flag,
                                               bf16* __restrict__ h_node, bf16* __restrict__ edge_max,
                                               bf16* __restrict__ out_a_b, float* __restrict__ out_a_f) {
    __shared__ int se[CAP];
    __shared__ int ss[CAP];
    __shared__ uint2 slg[CAP];
    __shared__ float sstat[8];
    __shared__ float2 red2[4][64];
    __shared__ float xr[4][EDGE_DIM];

    const int n = blockIdx.x;
    const int tid = threadIdx.x;
    const int isbf = flag[0];
    const int r0 = rowptr[n];
    const int deg = rowptr[n + 1] - r0;
    const int capn = deg < CAP ? deg : CAP;

    for (int j = tid; j < capn; j += 256) {
        int e = perm[r0 + j];
        se[j] = e;
        ss[j] = src[e];
        slg[j] = ((const uint2*)logits)[e];
    }
    __syncthreads();

    const int wv = tid >> 6, lane = tid & 63;

    // --- phase 1: per-head softmax stats (wave wv owns head wv) ---
    {
        float mloc = -3.0e38f;
        for (int j = lane; j < deg; j += 64) {
            float lg = (j < CAP) ? b2f_raw(((const u16*)&slg[j])[wv])
                                 : b2f_raw(((const u16*)logits)[(long)perm[r0 + j] * 4 + wv]);
            mloc = fmaxf(mloc, lg);
        }
#pragma unroll
        for (int m = 32; m; m >>= 1) mloc = fmaxf(mloc, __shfl_xor(mloc, m, 64));
        float sloc = 0.f;
        for (int j = lane; j < deg; j += 64) {
            float lg = (j < CAP) ? b2f_raw(((const u16*)&slg[j])[wv])
                                 : b2f_raw(((const u16*)logits)[(long)perm[r0 + j] * 4 + wv]);
            sloc += __expf(lg - mloc);
        }
#pragma unroll
        for (int m = 32; m; m >>= 1) sloc += __shfl_xor(sloc, m, 64);
        if (lane == 0) { sstat[wv] = mloc; sstat[4 + wv] = 1.f / fmaxf(sloc, 1e-9f); }
    }
    __syncthreads();

    // --- phase 2: weighted message gather (wave wv takes edges j = wv mod 4) ---
    {
        const int h = lane >> 4;   // cols {2*lane, 2*lane+1} are both in head lane>>4
        const float m = sstat[h], inv = sstat[4 + h];
        float ax = 0.f, ay = 0.f;
        const u32* fs = (const u32*)f_src;
#pragma unroll 2
        for (int j = wv; j < deg; j += 4) {
            int e, s; float lg;
            if (j < CAP) { e = se[j]; s = ss[j]; lg = b2f_raw(((const u16*)&slg[j])[h]); }
            else { e = perm[r0 + j]; s = src[e]; lg = b2f_raw(((const u16*)logits)[(long)e * 4 + h]); }
            float aj = __expf(lg - m) * inv;
            u32 p = fs[(long)s * 64 + lane];
            ax += b2f_raw((u16)(p & 0xFFFF)) * aj;
            ay += b2f_raw((u16)(p >> 16)) * aj;
            if ((lane & 15) == 0) {
                if (isbf) out_a_b[(long)e * 4 + h] = __float2bfloat16(aj);
                else      out_a_f[(long)e * 4 + h] = aj;
            }
        }
        red2[wv][lane] = make_float2(ax, ay);
    }
    __syncthreads();
    if (wv == 0) {
        float2 a0 = red2[0][lane], a1 = red2[1][lane], a2 = red2[2][lane], a3 = red2[3][lane];
        float sx = a0.x + a1.x + a2.x + a3.x;
        float sy = a0.y + a1.y + a2.y + a3.y;
        ((u32*)h_node)[(long)n * 64 + lane] = (u32)f2b_u16(sx) | ((u32)f2b_u16(sy) << 16);
    }

    // --- phase 3: edge encoder GEMM (4 edges/group, W^T in regs) + running max ---
    const int col = tid & 127;
    const int rr = tid >> 7;  // this thread handles edge slots rr and rr+2 within a group
    float4 wt[16];
    {
        const float4* wp = (const float4*)(w + OFF_WEDGE_T + col * EDGE_DIM);
#pragma unroll
        for (int kk = 0; kk < 16; kk++) wt[kk] = wp[kk];
    }
    const float bias = w[OFF_BEDGE + col];
    float vmax = -3.0e38f;
    for (int g0 = 0; g0 < deg; g0 += 4) {
        __syncthreads();
        if (isbf) {
            if (tid < 128) {                       // 4 rows x 32 u32
                int r = tid >> 5, kk = tid & 31;
                float v0 = 0.f, v1 = 0.f;
                if (g0 + r < deg) {
                    long e = (g0 + r < CAP) ? se[g0 + r] : perm[r0 + g0 + r];
                    u32 pp = ((const u32*)edge_feat)[e * 32 + kk];
                    v0 = b2f_raw((u16)(pp & 0xFFFF));
                    v1 = b2f_raw((u16)(pp >> 16));
                }
                xr[r][kk * 2] = v0;
                xr[r][kk * 2 + 1] = v1;
            }
        } else {
            int r = tid >> 6, kk = tid & 63;       // 4 rows x 64 f32
            float v = 0.f;
            if (g0 + r < deg) {
                long e = (g0 + r < CAP) ? se[g0 + r] : perm[r0 + g0 + r];
                v = ((const float*)edge_feat)[e * 64 + kk];
            }
            xr[r][kk] = v;
        }
        __syncthreads();
        float acc0 = bias, acc1 = bias;
#pragma unroll
        for (int kk = 0; kk < 16; kk++) {
            float4 wv4 = wt[kk];
            float4 x0 = ((const float4*)xr[rr])[kk];
            float4 x1 = ((const float4*)xr[rr + 2])[kk];
            acc0 += x0.x * wv4.x + x0.y * wv4.y + x0.z * wv4.z + x0.w * wv4.w;
            acc1 += x1.x * wv4.x + x1.y * wv4.y + x1.z * wv4.z + x1.w * wv4.w;
        }
        if (g0 + rr < deg)     vmax = fmaxf(vmax, acc0 > 0.f ? acc0 : __expf(acc0) - 1.f);
        if (g0 + rr + 2 < deg) vmax = fmaxf(vmax, acc1 > 0.f ? acc1 : __expf(acc1) - 1.f);
    }
    __syncthreads();
    ((float*)red2)[tid] = vmax;
    __syncthreads();
    if (tid < 128) {
        float v = fmaxf(((float*)red2)[tid], ((float*)red2)[tid + 128]);
        edge_max[(long)n * 128 + col] = __float2bfloat16(deg > 0 ? v : 0.f);
    }
}

// ---------- gated fusion (in-place over h_node) ----------
#define GATE_ROWS 8
__global__ __launch_bounds__(128) void k_gate(bf16* __restrict__ h_node,
                                              const bf16* __restrict__ edge_max,
                                              const float* __restrict__ w) {
    __shared__ float hn[GATE_ROWS][OUT_DIM];
    __shared__ float em[GATE_ROWS][OUT_DIM];
    int col = threadIdx.x;
    long row0 = (long)blockIdx.x * GATE_ROWS;
    for (int i = col; i < GATE_ROWS * OUT_DIM; i += 128) {
        hn[i >> 7][i & 127] = b2f(h_node[row0 * OUT_DIM + i]);
        em[i >> 7][i & 127] = b2f(edge_max[row0 * OUT_DIM + i]);
    }
    __syncthreads();
    float acc[GATE_ROWS];
    float bg = w[OFF_BGATE + col];
#pragma unroll
    for (int r = 0; r < GATE_ROWS; r++) acc[r] = bg;
    for (int k = 0; k < OUT_DIM; k++) {
        float wv = w[OFF_WGATE + k * OUT_DIM + col];
#pragma unroll
        for (int r = 0; r < GATE_ROWS; r++) acc[r] += hn[r][k] * wv;
    }
    for (int k = 0; k < OUT_DIM; k++) {
        float wv = w[OFF_WGATE + (OUT_DIM + k) * OUT_DIM + col];
#pragma unroll
        for (int r = 0; r < GATE_ROWS; r++) acc[r] += em[r][k] * wv;
    }
#pragma unroll
    for (int r = 0; r < GATE_ROWS; r++) {
        float g = 1.f / (1.f + expf(-acc[r]));
        h_node[(row0 + r) * OUT_DIM + col] = __float2bfloat16(g * hn[r][col] + (1.f - g) * em[r][col]);
    }
}

// ---------- output projection ----------
__global__ __launch_bounds__(128) void k_out(const bf16* __restrict__ h_fused,
                                             const float* __restrict__ w, const int* __restrict__ flag,
                                             bf16* __restrict__ out_b, float* __restrict__ out_f) {
    __shared__ float lds[PROJ_ROWS][OUT_DIM];
    int isbf = flag[0];
    int col = threadIdx.x;
    long row0 = (long)blockIdx.x * PROJ_ROWS;
    for (int i = col; i < PROJ_ROWS * OUT_DIM; i += 128)
        lds[i >> 7][i & 127] = b2f(h_fused[row0 * OUT_DIM + i]);
    __syncthreads();
    float acc[PROJ_ROWS];
    float bv = w[OFF_BOUT + col];
#pragma unroll
    for (int r = 0; r < PROJ_ROWS; r++) acc[r] = bv;
    for (int k = 0; k < OUT_DIM; k++) {
        float wv = w[OFF_WOUT + k * OUT_DIM + col];
#pragma unroll
        for (int r = 0; r < PROJ_ROWS; r++) acc[r] += lds[r][k] * wv;
    }
#pragma unroll
    for (int r = 0; r < PROJ_ROWS; r++) {
        long idx = (row0 + r) * OUT_DIM + col;
        if (isbf) out_b[idx] = __float2bfloat16(acc[r]);
        else      out_f[idx] = acc[r];
    }
}

extern "C" void kernel_launch(void* const* d_in, const int* in_sizes, int n_in,
                              void* d_out, int out_size, void* d_ws, size_t ws_size,
                              hipStream_t stream) {
    const void* node_feat = d_in[0];
    const void* edge_feat = d_in[1];
    const int* src = (const int*)d_in[2];
    const int* dst = (const int*)d_in[3];

    // workspace layout (bytes), total ~50.6 MB (proven-safe < 59.6 MB):
    //   0        .. 12.8M : f_src   bf16 [N][128]
    //   12.8M    .. 25.6M : f_dst   bf16 [N][128]  -> overlaid by edge_max after k_logits2
    //   25.6M    .. 32.0M : logits  bf16 [E][4]
    //   32.0M    .. 44.8M : h_node  bf16 [N][128]  (h_fused in-place)
    //   44.8M..  : deg, rowptr, cursor, perm, wcanon, flag
    char* ws = (char*)d_ws;
    bf16* f_src = (bf16*)ws;
    bf16* f_dst = (bf16*)(ws + 12800000);
    bf16* edge_max = (bf16*)(ws + 12800000);  // overlays f_dst (dead after k_logits2)
    bf16* logits = (bf16*)(ws + 25600000);
    bf16* h_node = (bf16*)(ws + 32000000);
    int* deg = (int*)(ws + 44800000);
    int* rowptr = (int*)(ws + 45000000);
    int* cursor = (int*)(ws + 45200008);
    int* perm = (int*)(ws + 45400016);
    float* wcanon = (float*)(ws + 48600032);
    int* flag = (int*)(ws + 48996320);

    bf16* out_b = (bf16*)d_out;
    float* out_f = (float*)d_out;
    bf16* out_a_b = out_b + (size_t)N_NODES * OUT_DIM;
    float* out_a_f = out_f + (size_t)N_NODES * OUT_DIM;

    k_detect<<<1, 256, 0, stream>>>(node_feat, flag);
    k_wconv<<<(W_TOTAL + 255) / 256, 256, 0, stream>>>(d_in[4], d_in[5], d_in[6], d_in[7], d_in[8],
                                                       d_in[9], d_in[10], d_in[11], d_in[12],
                                                       d_in[13], d_in[14], wcanon, flag);
    k_zero<<<(N_NODES + 255) / 256, 256, 0, stream>>>(deg);
    k_hist<<<(N_EDGES + 255) / 256, 256, 0, stream>>>(dst, deg);
    k_scan<<<1, 1024, 0, stream>>>(deg, rowptr, cursor);
    k_permute<<<(N_EDGES + 255) / 256, 256, 0, stream>>>(dst, cursor, perm);
    k_proj<<<N_NODES / PROJ_ROWS, 128, 0, stream>>>(node_feat, wcanon, flag, f_src, f_dst);
    k_logits2<<<N_EDGES / 32, 256, 0, stream>>>(f_src, f_dst, src, dst, wcanon, logits);
    k_node2<<<N_NODES, 256, 0, stream>>>(rowptr, perm, src, f_src, logits, edge_feat,
                                         wcanon, flag, h_node, edge_max, out_a_b, out_a_f);
    k_gate<<<N_NODES / GATE_ROWS, 128, 0, stream>>>(h_node, edge_max, wcanon);
    k_out<<<N_NODES / PROJ_ROWS, 128, 0, stream>>>(h_node, wcanon, flag, out_b, out_f);
}